// Round 5
// baseline (121.630 us; speedup 1.0000x reference)
//
#include <hip/hip_runtime.h>
#include <hip/hip_bf16.h>

#define NB   64
#define SL   1024
#define EMB  128
#define NSK  1000
#define TI   64    // i-tile rows
#define JB   32    // j per block
#define NS   2     // split of i-tiles per j-tile

#define TB_ELEMS 768000
#define ACC_BYTE_OFF (TB_ELEMS * 2)   // acc: [NS][NB][SL] float = 512 KB

// byte offsets into the bf16 table blob
#define AI_B 0
#define BI_B 512000
#define AS_B 1024000
#define BS_B 1280000

using short8  = __attribute__((ext_vector_type(8))) short;
using floatx4 = __attribute__((ext_vector_type(4))) float;

// log5(x) = log2(x) * INV_LOG2_5
#define INV_LOG2_5 0.43067655807339306f

__device__ inline unsigned cvt2(float x, float y) {
    float2 f; f.x = x; f.y = y;
    __hip_bfloat162 h = __float22bfloat162_rn(f);
    unsigned u; __builtin_memcpy(&u, &h, sizeof(u));
    return u;
}

// ---- one-time fp32 -> bf16 table conversion (8 elems/thread) ----
extern "C" __global__ __launch_bounds__(256)
void cvt_tables(const float* __restrict__ ai, const float* __restrict__ bi,
                const float* __restrict__ as, const float* __restrict__ bs,
                unsigned short* __restrict__ dst)
{
    const int t = blockIdx.x * 256 + threadIdx.x;   // 96000 threads
    const long e = (long)t * 8;
    const float* src;
    if      (e < 256000) src = ai + e;
    else if (e < 512000) src = bi + (e - 256000);
    else if (e < 640000) src = as + (e - 512000);
    else                 src = bs + (e - 640000);
    float4 f0 = *(const float4*)src;
    float4 f1 = *(const float4*)(src + 4);
    uint4 pk;
    pk.x = cvt2(f0.x, f0.y); pk.y = cvt2(f0.z, f0.w);
    pk.z = cvt2(f1.x, f1.y); pk.w = cvt2(f1.z, f1.w);
    *(uint4*)(dst + e) = pk;
}

// exact fp32 path for duplicate-timestamp pairs (dt==0, i<j)
__device__ float fixup_pair(const float* __restrict__ air,
                            const float* __restrict__ bir,
                            const float* __restrict__ asr,
                            const float* __restrict__ bsr) {
    float da = 0.f, db = 0.f;
#pragma unroll 8
    for (int k = 0; k < EMB; k += 4) {
        float4 a  = *(const float4*)(air + k);
        float4 s  = *(const float4*)(asr + k);
        float4 bq = *(const float4*)(bir + k);
        float4 tt = *(const float4*)(bsr + k);
        da += a.x * s.x + a.y * s.y + a.z * s.z + a.w * s.w;
        db += bq.x * tt.x + bq.y * tt.y + bq.z * tt.z + bq.w * tt.w;
    }
    float beta = fminf(fmaxf(db + 1.f, 0.f), 10.f);
    return da * __expf(beta * 14.30676558073393f);
}

// ---- per-tile staging: thread carries 64B of BOTH mats for one row ----
// coverage: 256 threads = 64 rows (tid>>2) x 4 quarter-rows (tid&3)
//           x 2 mats each = 64*256B*2 = 32 KB per tile. (full tile!)
struct Stage2 { uint4 a0, a1, a2, a3, b0, b1, b2, b3; };

__device__ __forceinline__ Stage2 stage_load2(const char* __restrict__ tbc,
                                              int intr, int sq)
{
    const long ab = (long)intr * 256 + sq * 64;
    const char* pA = tbc + AI_B + ab;
    const char* pB = tbc + BI_B + ab;
    Stage2 s;
    s.a0 = *(const uint4*)(pA);      s.a1 = *(const uint4*)(pA + 16);
    s.a2 = *(const uint4*)(pA + 32); s.a3 = *(const uint4*)(pA + 48);
    s.b0 = *(const uint4*)(pB);      s.b1 = *(const uint4*)(pB + 16);
    s.b2 = *(const uint4*)(pB + 32); s.b3 = *(const uint4*)(pB + 48);
    return s;
}

// proven swizzle (0 conflicts measured r1): chunk c of row r at byte
// ((( (c>>1)^(r&7) ) + ((c&1)<<3)) << 4) within the row's 256B.
__device__ __forceinline__ void stage_write2(char* buf, int srow, int wslot,
                                             const Stage2& s)
{
    char* pA  = buf + srow * 256 + wslot;            // chunks 4sq, 4sq+1
    char* pAx = buf + srow * 256 + (wslot ^ 16);     // chunks 4sq+2, 4sq+3
    *(uint4*)(pA)        = s.a0;  *(uint4*)(pA + 128)  = s.a1;
    *(uint4*)(pAx)       = s.a2;  *(uint4*)(pAx + 128) = s.a3;
    *(uint4*)(pA + 16384)  = s.b0;  *(uint4*)(pA + 16384 + 128)  = s.b1;
    *(uint4*)(pAx + 16384) = s.b2;  *(uint4*)(pAx + 16384 + 128) = s.b3;
}

// ============================================================================
// hawkes_main v7: 32-j blocks. Wave w owns i-rows [w*16,+16) of each 64-row
// i-tile and ALL 32 j (B-frags = 64 VGPR). Single 32 KB LDS buffer; register
// staging (Stage2) with prefetch issued AFTER the publish barrier so the
// barrier's vmcnt drain never serializes it. 2 barriers/tile. No runtime-
// indexed arrays (everything static). launch_bounds(256,3) -> 12 waves/CU.
// ============================================================================
extern "C" __global__ __launch_bounds__(256, 3)
void hawkes_main(const int*   __restrict__ inp,     // (B,4,L) int32
                 const unsigned short* __restrict__ tb,  // bf16 tables
                 float*       __restrict__ acc)     // [NS][NB][SL] partials
{
    __shared__ uint4 ldsq[2048];                    // 32 KB
    char* ldsc = (char*)ldsq;

    const int bid  = blockIdx.x;                    // grid = NB * 32 * NS = 4096
    const int b    = bid & (NB - 1);
    const int r_   = bid >> 6;                 // 0..63
    const int jt   = 31 - (r_ >> 1);           // j-tile (32 wide), heavy first
    const int s    = r_ & 1;
    const int tid  = threadIdx.x;
    const int w    = tid >> 6;                 // wave id -> i-slab
    const int l    = tid & 63;
    const int quad = l >> 4;
    const int col  = l & 15;
    const int wrow = w * 16;

    const int* __restrict__ binp = inp + b * 4 * SL;
    const char* __restrict__ tbc = (const char*)tb;
    const int jbase = jt * JB;

    const int jtop = jt >> 1;                  // highest valid 64-row i-tile
    const int nt   = (s <= jtop) ? ((jtop - s) >> 1) + 1 : 0;

    // ---- per-lane j times (2 strips of 16 j) ----
    int tjv0 = binp[3 * SL + jbase + col];
    int tjv1 = binp[3 * SL + jbase + 16 + col];

    // ---- stage skill rows of the block's 32 j into LDS (once) ----
    // thread: row = tid>>3 (0..31), chunk-pair c2 = tid&7 -> chunks 2c2,2c2+1
    // of both mats (64 B/thread). slot(c) = c ^ (row&15).
    {
        const int row = tid >> 3;
        const int c2  = tid & 7;
        const int skj = binp[jbase + row];
        const char* srcA = tbc + AS_B + (long)skj * 256 + c2 * 32;
        const char* srcB = tbc + BS_B + (long)skj * 256 + c2 * 32;
        uint4 qa0 = *(const uint4*)(srcA),      qa1 = *(const uint4*)(srcA + 16);
        uint4 qb0 = *(const uint4*)(srcB),      qb1 = *(const uint4*)(srcB + 16);
        const int rx = (row & 15) << 4;
        char* dst = ldsc + row * 256;
        *(uint4*)(dst + (((2 * c2)     << 4) ^ rx)) = qa0;
        *(uint4*)(dst + (((2 * c2 + 1) << 4) ^ rx)) = qa1;
        *(uint4*)(dst + 8192 + (((2 * c2)     << 4) ^ rx)) = qb0;
        *(uint4*)(dst + 8192 + (((2 * c2 + 1) << 4) ^ rx)) = qb1;
    }
    __syncthreads();

    // ---- B fragments (2 strips x 4 ks x 2 mats = 64 VGPR) ----
    short8 bfa[2][4], bfb[2][4];
#pragma unroll
    for (int strip = 0; strip < 2; ++strip) {
        const int row   = strip * 16 + col;
        const int rbase = row * 256;
        const int rx    = (row & 15) << 4;
#pragma unroll
        for (int ks = 0; ks < 4; ++ks) {
            const int cb = ((quad + ks * 4) << 4) ^ rx;
            bfa[strip][ks] = *(const short8*)(ldsc + rbase + cb);
            bfb[strip][ks] = *(const short8*)(ldsc + 8192 + rbase + cb);
        }
    }

    // ---- staging role ----
    const int srow  = tid >> 2;                // 0..63: row within tile
    const int sq    = tid & 3;                 // quarter-row
    const int wslot = (((2 * sq) ^ (srow & 7)) << 4);

    // ---- lane-invariant swizzled read offsets for the wave's i-slab ----
    int roff[4];
    {
        const int qh = quad >> 1, ql = quad & 1, c7 = col & 7;
#pragma unroll
        for (int ks = 0; ks < 4; ++ks)
            roff[ks] = (wrow + col) * 256 + ql * 128 + (((2 * ks + qh) ^ c7) << 4);
    }

    float sum0 = 0.f, sum1 = 0.f;

    if (nt > 0) {
        // prolog: issue tile-0 loads (overlap the bf ds_reads above)
        Stage2 rS;
        {
            const int arow = s * TI + srow;
            rS = stage_load2(tbc, binp[arow] + binp[2 * SL + arow] * NSK, sq);
        }
        __syncthreads();                       // all bf reads done block-wide

#pragma unroll 1
        for (int t = 0; t < nt; ++t) {
            stage_write2(ldsc, srow, wslot, rS);   // tile t -> LDS (waits rS vmcnt)
            __syncthreads();                       // publish tile t

            // prefetch tile t+1 AFTER the barrier: its latency is hidden by
            // the compute phase and only drained at the next barrier.
            if (t + 1 < nt) {
                const int arow = (s + 2 * (t + 1)) * TI + srow;
                rS = stage_load2(tbc, binp[arow] + binp[2 * SL + arow] * NSK, sq);
            }

            const int itrow = (s + 2 * t) * TI;
            short8 av[4], bv[4];
#pragma unroll
            for (int ks = 0; ks < 4; ++ks) {
                av[ks] = *(const short8*)(ldsc + roff[ks]);
                bv[ks] = *(const short8*)(ldsc + 16384 + roff[ks]);
            }
            const int4 t4 = *(const int4*)(binp + 3 * SL + itrow + wrow + quad * 4);

            floatx4 aa0 = {0.f,0.f,0.f,0.f}, aa1 = {0.f,0.f,0.f,0.f};
            floatx4 bb0 = {1.f,1.f,1.f,1.f}, bb1 = {1.f,1.f,1.f,1.f}; // +1.0 folded
#pragma unroll
            for (int ks = 0; ks < 4; ++ks) {
                aa0 = __builtin_amdgcn_mfma_f32_16x16x32_bf16(av[ks], bfa[0][ks], aa0, 0, 0, 0);
                bb0 = __builtin_amdgcn_mfma_f32_16x16x32_bf16(bv[ks], bfb[0][ks], bb0, 0, 0, 0);
                aa1 = __builtin_amdgcn_mfma_f32_16x16x32_bf16(av[ks], bfa[1][ks], aa1, 0, 0, 0);
                bb1 = __builtin_amdgcn_mfma_f32_16x16x32_bf16(bv[ks], bfb[1][ks], bb1, 0, 0, 0);
            }

            __syncthreads();                       // reads of tile t done

            // epilogue: i = itrow + wrow + quad*4 + rr ; j = jbase + strip*16 + col
#pragma unroll
            for (int rr = 0; rr < 4; ++rr) {
                const int ti = (rr == 0) ? t4.x : (rr == 1) ? t4.y : (rr == 2) ? t4.z : t4.w;
                {
                    const int dt = tjv0 - ti;
                    float lc  = __log2f((float)dt);
                    float nb  = fminf(fmaxf(bb0[rr], 0.f), 10.f) * (-INV_LOG2_5);
                    float arg = (dt > 0) ? nb * lc : -__builtin_inff();
                    sum0 += aa0[rr] * __builtin_amdgcn_exp2f(arg);
                }
                {
                    const int dt = tjv1 - ti;
                    float lc  = __log2f((float)dt);
                    float nb  = fminf(fmaxf(bb1[rr], 0.f), 10.f) * (-INV_LOG2_5);
                    float arg = (dt > 0) ? nb * lc : -__builtin_inff();
                    sum1 += aa1[rr] * __builtin_amdgcn_exp2f(arg);
                }
            }
        }
    } else {
        __syncthreads();                       // match prolog barrier count (uniform per block anyway)
    }

    // ---- reduce: quads within wave, then the 4 i-slab waves via LDS ----
    sum0 += __shfl_xor(sum0, 16, 64);
    sum0 += __shfl_xor(sum0, 32, 64);
    sum1 += __shfl_xor(sum1, 16, 64);
    sum1 += __shfl_xor(sum1, 32, 64);

    __syncthreads();                           // tile LDS dead; reuse as red[4][32]
    float* red = (float*)ldsc;
    if (quad == 0) {
        red[w * 32 + col]      = sum0;
        red[w * 32 + 16 + col] = sum1;
    }
    __syncthreads();
    if (w == 0 && l < JB) {
        const float tot = red[l] + red[32 + l] + red[64 + l] + red[96 + l];
        acc[(((long)s * NB + b) << 10) + jbase + l] = tot;
    }
}

extern "C" __global__ __launch_bounds__(256)
void hawkes_finalize(const int* __restrict__ inp, const float* __restrict__ pbase,
                     const float* __restrict__ sbase,
                     const float* __restrict__ ai, const float* __restrict__ as,
                     const float* __restrict__ bi, const float* __restrict__ bs,
                     const float* __restrict__ acc, float* __restrict__ out)
{
    const int t = blockIdx.x * 256 + threadIdx.x;   // 65536
    const int b = t >> 10, j = t & (SL - 1);
    const int* binp = inp + b * 4 * SL;
    const int tj   = binp[3 * SL + j];
    const int sk_j = binp[j];

    // exact fp32 correction for duplicate-timestamp pairs (adjacent in sorted order)
    float corr = 0.f;
    for (int i = j - 1; i >= 0 && binp[3 * SL + i] == tj; --i) {
        const int ski = binp[i], li = binp[2 * SL + i];
        const long intr = ski + (long)li * NSK;
        corr += fixup_pair(ai + intr * EMB, bi + intr * EMB,
                           as + (long)sk_j * EMB, bs + (long)sk_j * EMB);
    }

    float sum = acc[t] + acc[NB * SL + t] + corr;
    const float x = pbase[binp[SL + j]] + sbase[sk_j] + sum;
    out[t] = 1.f / (1.f + __expf(-x));
}

extern "C" void kernel_launch(void* const* d_in, const int* in_sizes, int n_in,
                              void* d_out, int out_size, void* d_ws, size_t ws_size,
                              hipStream_t stream) {
    const int*   inp = (const int*)d_in[0];
    const float* pb  = (const float*)d_in[1];
    const float* sb  = (const float*)d_in[2];
    const float* ai  = (const float*)d_in[3];
    const float* as  = (const float*)d_in[4];
    const float* bi  = (const float*)d_in[5];
    const float* bs  = (const float*)d_in[6];

    unsigned short* tb  = (unsigned short*)d_ws;
    float*          acc = (float*)((char*)d_ws + ACC_BYTE_OFF);

    cvt_tables<<<dim3(96000 / 256), dim3(256), 0, stream>>>(ai, bi, as, bs, tb);
    hawkes_main<<<dim3(NB * JB * NS / 1), dim3(256), 0, stream>>>(inp, tb, acc);
    hawkes_finalize<<<dim3(NB * SL / 256), dim3(256), 0, stream>>>(
        inp, pb, sb, ai, as, bi, bs, acc, (float*)d_out);
}

// Round 6
// 121.151 us; speedup vs baseline: 1.0040x; 1.0040x over previous
//
#include <hip/hip_runtime.h>
#include <hip/hip_bf16.h>

#define NB   64
#define SL   1024
#define EMB  128
#define NSK  1000
#define TI   64    // i-tile rows
#define JB   32    // j per block
#define NS   2     // split of i-tiles per j-tile

#define TB_ELEMS 768000
#define ACC_BYTE_OFF (TB_ELEMS * 2)   // acc: [NS][NB][SL] float = 512 KB

// byte offsets into the bf16 table blob
#define AI_B 0
#define BI_B 512000
#define AS_B 1024000
#define BS_B 1280000

using short8  = __attribute__((ext_vector_type(8))) short;
using floatx4 = __attribute__((ext_vector_type(4))) float;

// log5(x) = log2(x) * INV_LOG2_5
#define INV_LOG2_5 0.43067655807339306f

// Raw barrier with lgkm-only ordering: LDS publish/consume needs lgkmcnt(0),
// but vmcnt (global prefetch) free-runs across it. This is the whole point:
// __syncthreads() compiles to s_waitcnt vmcnt(0) lgkmcnt(0) + s_barrier,
// draining our prefetch at every barrier (T3/T4, learn_hip m194-m199).
#define RAW_BAR_LGKM() do {                                   \
    asm volatile("s_waitcnt lgkmcnt(0)" ::: "memory");        \
    __builtin_amdgcn_s_barrier();                             \
    asm volatile("" ::: "memory");                            \
    __builtin_amdgcn_sched_barrier(0);                        \
} while (0)

__device__ inline unsigned cvt2(float x, float y) {
    float2 f; f.x = x; f.y = y;
    __hip_bfloat162 h = __float22bfloat162_rn(f);
    unsigned u; __builtin_memcpy(&u, &h, sizeof(u));
    return u;
}

// ---- one-time fp32 -> bf16 table conversion (8 elems/thread) ----
extern "C" __global__ __launch_bounds__(256)
void cvt_tables(const float* __restrict__ ai, const float* __restrict__ bi,
                const float* __restrict__ as, const float* __restrict__ bs,
                unsigned short* __restrict__ dst)
{
    const int t = blockIdx.x * 256 + threadIdx.x;   // 96000 threads
    const long e = (long)t * 8;
    const float* src;
    if      (e < 256000) src = ai + e;
    else if (e < 512000) src = bi + (e - 256000);
    else if (e < 640000) src = as + (e - 512000);
    else                 src = bs + (e - 640000);
    float4 f0 = *(const float4*)src;
    float4 f1 = *(const float4*)(src + 4);
    uint4 pk;
    pk.x = cvt2(f0.x, f0.y); pk.y = cvt2(f0.z, f0.w);
    pk.z = cvt2(f1.x, f1.y); pk.w = cvt2(f1.z, f1.w);
    *(uint4*)(dst + e) = pk;
}

// exact fp32 path for duplicate-timestamp pairs (dt==0, i<j)
__device__ float fixup_pair(const float* __restrict__ air,
                            const float* __restrict__ bir,
                            const float* __restrict__ asr,
                            const float* __restrict__ bsr) {
    float da = 0.f, db = 0.f;
#pragma unroll 8
    for (int k = 0; k < EMB; k += 4) {
        float4 a  = *(const float4*)(air + k);
        float4 s  = *(const float4*)(asr + k);
        float4 bq = *(const float4*)(bir + k);
        float4 tt = *(const float4*)(bsr + k);
        da += a.x * s.x + a.y * s.y + a.z * s.z + a.w * s.w;
        db += bq.x * tt.x + bq.y * tt.y + bq.z * tt.z + bq.w * tt.w;
    }
    float beta = fminf(fmaxf(db + 1.f, 0.f), 10.f);
    return da * __expf(beta * 14.30676558073393f);
}

// ---- per-tile staging: thread carries 64B of BOTH mats for one row ----
// coverage: 256 threads = 64 rows (tid>>2) x 4 quarter-rows (tid&3)
//           x 2 mats each = 64*256B*2 = 32 KB per tile. (full tile!)
struct Stage2 { uint4 a0, a1, a2, a3, b0, b1, b2, b3; };

__device__ __forceinline__ Stage2 stage_load2(const char* __restrict__ tbc,
                                              int intr, int sq)
{
    const long ab = (long)intr * 256 + sq * 64;
    const char* pA = tbc + AI_B + ab;
    const char* pB = tbc + BI_B + ab;
    Stage2 s;
    s.a0 = *(const uint4*)(pA);      s.a1 = *(const uint4*)(pA + 16);
    s.a2 = *(const uint4*)(pA + 32); s.a3 = *(const uint4*)(pA + 48);
    s.b0 = *(const uint4*)(pB);      s.b1 = *(const uint4*)(pB + 16);
    s.b2 = *(const uint4*)(pB + 32); s.b3 = *(const uint4*)(pB + 48);
    return s;
}

// proven swizzle (0 conflicts measured r1): chunk c of row r at byte
// ((( (c>>1)^(r&7) ) + ((c&1)<<3)) << 4) within the row's 256B.
__device__ __forceinline__ void stage_write2(char* buf, int srow, int wslot,
                                             const Stage2& s)
{
    char* pA  = buf + srow * 256 + wslot;            // chunks 4sq, 4sq+1
    char* pAx = buf + srow * 256 + (wslot ^ 16);     // chunks 4sq+2, 4sq+3
    *(uint4*)(pA)        = s.a0;  *(uint4*)(pA + 128)  = s.a1;
    *(uint4*)(pAx)       = s.a2;  *(uint4*)(pAx + 128) = s.a3;
    *(uint4*)(pA + 16384)  = s.b0;  *(uint4*)(pA + 16384 + 128)  = s.b1;
    *(uint4*)(pAx + 16384) = s.b2;  *(uint4*)(pAx + 16384 + 128) = s.b3;
}

// ============================================================================
// hawkes_main v8: identical structure/layout/math to v7 (passed), with the
// hot-loop __syncthreads() replaced by raw s_barrier + lgkmcnt(0)-only waits.
// vmcnt free-runs across barriers, so the Stage2 prefetch issued after the
// publish barrier lands under the MFMA+epilogue phase instead of being
// drained at the next barrier. t4 (times) is loaded BEFORE the prefetch so
// its epilogue use waits vmcnt(8), keeping the prefetch in flight.
// ============================================================================
extern "C" __global__ __launch_bounds__(256, 3)
void hawkes_main(const int*   __restrict__ inp,     // (B,4,L) int32
                 const unsigned short* __restrict__ tb,  // bf16 tables
                 float*       __restrict__ acc)     // [NS][NB][SL] partials
{
    __shared__ uint4 ldsq[2048];                    // 32 KB
    char* ldsc = (char*)ldsq;

    const int bid  = blockIdx.x;                    // grid = NB * 32 * NS = 4096
    const int b    = bid & (NB - 1);
    const int r_   = bid >> 6;                 // 0..63
    const int jt   = 31 - (r_ >> 1);           // j-tile (32 wide), heavy first
    const int s    = r_ & 1;
    const int tid  = threadIdx.x;
    const int w    = tid >> 6;                 // wave id -> i-slab
    const int l    = tid & 63;
    const int quad = l >> 4;
    const int col  = l & 15;
    const int wrow = w * 16;

    const int* __restrict__ binp = inp + b * 4 * SL;
    const char* __restrict__ tbc = (const char*)tb;
    const int jbase = jt * JB;

    const int jtop = jt >> 1;                  // highest valid 64-row i-tile
    const int nt   = (s <= jtop) ? ((jtop - s) >> 1) + 1 : 0;

    // ---- per-lane j times (2 strips of 16 j) ----
    int tjv0 = binp[3 * SL + jbase + col];
    int tjv1 = binp[3 * SL + jbase + 16 + col];

    // ---- stage skill rows of the block's 32 j into LDS (once) ----
    {
        const int row = tid >> 3;
        const int c2  = tid & 7;
        const int skj = binp[jbase + row];
        const char* srcA = tbc + AS_B + (long)skj * 256 + c2 * 32;
        const char* srcB = tbc + BS_B + (long)skj * 256 + c2 * 32;
        uint4 qa0 = *(const uint4*)(srcA),      qa1 = *(const uint4*)(srcA + 16);
        uint4 qb0 = *(const uint4*)(srcB),      qb1 = *(const uint4*)(srcB + 16);
        const int rx = (row & 15) << 4;
        char* dst = ldsc + row * 256;
        *(uint4*)(dst + (((2 * c2)     << 4) ^ rx)) = qa0;
        *(uint4*)(dst + (((2 * c2 + 1) << 4) ^ rx)) = qa1;
        *(uint4*)(dst + 8192 + (((2 * c2)     << 4) ^ rx)) = qb0;
        *(uint4*)(dst + 8192 + (((2 * c2 + 1) << 4) ^ rx)) = qb1;
    }
    __syncthreads();

    // ---- B fragments (2 strips x 4 ks x 2 mats = 64 VGPR) ----
    short8 bfa[2][4], bfb[2][4];
#pragma unroll
    for (int strip = 0; strip < 2; ++strip) {
        const int row   = strip * 16 + col;
        const int rbase = row * 256;
        const int rx    = (row & 15) << 4;
#pragma unroll
        for (int ks = 0; ks < 4; ++ks) {
            const int cb = ((quad + ks * 4) << 4) ^ rx;
            bfa[strip][ks] = *(const short8*)(ldsc + rbase + cb);
            bfb[strip][ks] = *(const short8*)(ldsc + 8192 + rbase + cb);
        }
    }

    // ---- staging role ----
    const int srow  = tid >> 2;                // 0..63: row within tile
    const int sq    = tid & 3;                 // quarter-row
    const int wslot = (((2 * sq) ^ (srow & 7)) << 4);

    // ---- lane-invariant swizzled read offsets for the wave's i-slab ----
    int roff[4];
    {
        const int qh = quad >> 1, ql = quad & 1, c7 = col & 7;
#pragma unroll
        for (int ks = 0; ks < 4; ++ks)
            roff[ks] = (wrow + col) * 256 + ql * 128 + (((2 * ks + qh) ^ c7) << 4);
    }

    float sum0 = 0.f, sum1 = 0.f;

    if (nt > 0) {
        // prolog: issue tile-0 loads (overlap the bf ds_reads above)
        Stage2 rS;
        {
            const int arow = s * TI + srow;
            rS = stage_load2(tbc, binp[arow] + binp[2 * SL + arow] * NSK, sq);
        }
        RAW_BAR_LGKM();                        // bf reads done; rS loads keep flying

#pragma unroll 1
        for (int t = 0; t < nt; ++t) {
            stage_write2(ldsc, srow, wslot, rS);   // vmcnt wait on rS here only
            RAW_BAR_LGKM();                        // publish tile t (no vmcnt drain)

            const int itrow = (s + 2 * t) * TI;
            // times load FIRST so its epilogue use waits vmcnt(8), not 0
            const int4 t4 = *(const int4*)(binp + 3 * SL + itrow + wrow + quad * 4);

            // prefetch tile t+1: latency hidden under MFMA + epilogue, drained
            // only at next iteration's stage_write2 (register dependency).
            if (t + 1 < nt) {
                const int arow = (s + 2 * (t + 1)) * TI + srow;
                rS = stage_load2(tbc, binp[arow] + binp[2 * SL + arow] * NSK, sq);
            }

            short8 av[4], bv[4];
#pragma unroll
            for (int ks = 0; ks < 4; ++ks) {
                av[ks] = *(const short8*)(ldsc + roff[ks]);
                bv[ks] = *(const short8*)(ldsc + 16384 + roff[ks]);
            }

            floatx4 aa0 = {0.f,0.f,0.f,0.f}, aa1 = {0.f,0.f,0.f,0.f};
            floatx4 bb0 = {1.f,1.f,1.f,1.f}, bb1 = {1.f,1.f,1.f,1.f}; // +1.0 folded
#pragma unroll
            for (int ks = 0; ks < 4; ++ks) {
                aa0 = __builtin_amdgcn_mfma_f32_16x16x32_bf16(av[ks], bfa[0][ks], aa0, 0, 0, 0);
                bb0 = __builtin_amdgcn_mfma_f32_16x16x32_bf16(bv[ks], bfb[0][ks], bb0, 0, 0, 0);
                aa1 = __builtin_amdgcn_mfma_f32_16x16x32_bf16(av[ks], bfa[1][ks], aa1, 0, 0, 0);
                bb1 = __builtin_amdgcn_mfma_f32_16x16x32_bf16(bv[ks], bfb[1][ks], bb1, 0, 0, 0);
            }

            RAW_BAR_LGKM();                        // reads of tile t done (lgkm only)

            // epilogue: i = itrow + wrow + quad*4 + rr ; j = jbase + strip*16 + col
#pragma unroll
            for (int rr = 0; rr < 4; ++rr) {
                const int ti = (rr == 0) ? t4.x : (rr == 1) ? t4.y : (rr == 2) ? t4.z : t4.w;
                {
                    const int dt = tjv0 - ti;
                    float lc  = __log2f((float)dt);
                    float nb  = fminf(fmaxf(bb0[rr], 0.f), 10.f) * (-INV_LOG2_5);
                    float arg = (dt > 0) ? nb * lc : -__builtin_inff();
                    sum0 += aa0[rr] * __builtin_amdgcn_exp2f(arg);
                }
                {
                    const int dt = tjv1 - ti;
                    float lc  = __log2f((float)dt);
                    float nb  = fminf(fmaxf(bb1[rr], 0.f), 10.f) * (-INV_LOG2_5);
                    float arg = (dt > 0) ? nb * lc : -__builtin_inff();
                    sum1 += aa1[rr] * __builtin_amdgcn_exp2f(arg);
                }
            }
        }
    } else {
        __syncthreads();                       // match prolog barrier (block-uniform)
    }

    // ---- reduce: quads within wave, then the 4 i-slab waves via LDS ----
    sum0 += __shfl_xor(sum0, 16, 64);
    sum0 += __shfl_xor(sum0, 32, 64);
    sum1 += __shfl_xor(sum1, 16, 64);
    sum1 += __shfl_xor(sum1, 32, 64);

    __syncthreads();                           // full drain; tile LDS dead -> red[4][32]
    float* red = (float*)ldsc;
    if (quad == 0) {
        red[w * 32 + col]      = sum0;
        red[w * 32 + 16 + col] = sum1;
    }
    __syncthreads();
    if (w == 0 && l < JB) {
        const float tot = red[l] + red[32 + l] + red[64 + l] + red[96 + l];
        acc[(((long)s * NB + b) << 10) + jbase + l] = tot;
    }
}

extern "C" __global__ __launch_bounds__(256)
void hawkes_finalize(const int* __restrict__ inp, const float* __restrict__ pbase,
                     const float* __restrict__ sbase,
                     const float* __restrict__ ai, const float* __restrict__ as,
                     const float* __restrict__ bi, const float* __restrict__ bs,
                     const float* __restrict__ acc, float* __restrict__ out)
{
    const int t = blockIdx.x * 256 + threadIdx.x;   // 65536
    const int b = t >> 10, j = t & (SL - 1);
    const int* binp = inp + b * 4 * SL;
    const int tj   = binp[3 * SL + j];
    const int sk_j = binp[j];

    // exact fp32 correction for duplicate-timestamp pairs (adjacent in sorted order)
    float corr = 0.f;
    for (int i = j - 1; i >= 0 && binp[3 * SL + i] == tj; --i) {
        const int ski = binp[i], li = binp[2 * SL + i];
        const long intr = ski + (long)li * NSK;
        corr += fixup_pair(ai + intr * EMB, bi + intr * EMB,
                           as + (long)sk_j * EMB, bs + (long)sk_j * EMB);
    }

    float sum = acc[t] + acc[NB * SL + t] + corr;
    const float x = pbase[binp[SL + j]] + sbase[sk_j] + sum;
    out[t] = 1.f / (1.f + __expf(-x));
}

extern "C" void kernel_launch(void* const* d_in, const int* in_sizes, int n_in,
                              void* d_out, int out_size, void* d_ws, size_t ws_size,
                              hipStream_t stream) {
    const int*   inp = (const int*)d_in[0];
    const float* pb  = (const float*)d_in[1];
    const float* sb  = (const float*)d_in[2];
    const float* ai  = (const float*)d_in[3];
    const float* as  = (const float*)d_in[4];
    const float* bi  = (const float*)d_in[5];
    const float* bs  = (const float*)d_in[6];

    unsigned short* tb  = (unsigned short*)d_ws;
    float*          acc = (float*)((char*)d_ws + ACC_BYTE_OFF);

    cvt_tables<<<dim3(96000 / 256), dim3(256), 0, stream>>>(ai, bi, as, bs, tb);
    hawkes_main<<<dim3(NB * JB * NS), dim3(256), 0, stream>>>(inp, tb, acc);
    hawkes_finalize<<<dim3(NB * SL / 256), dim3(256), 0, stream>>>(
        inp, pb, sb, ai, as, bi, bs, acc, (float*)d_out);
}

// Round 7
// 115.030 us; speedup vs baseline: 1.0574x; 1.0532x over previous
//
#include <hip/hip_runtime.h>
#include <hip/hip_bf16.h>

#define NB   64
#define SL   1024
#define EMB  128
#define NSK  1000
#define TI   64    // i-tile rows

#define TB_ELEMS 768000

// byte offsets into the bf16 table blob
#define AI_B 0
#define BI_B 512000
#define AS_B 1024000
#define BS_B 1280000

using short8  = __attribute__((ext_vector_type(8))) short;
using floatx4 = __attribute__((ext_vector_type(4))) float;

// log5(x) = log2(x) * INV_LOG2_5
#define INV_LOG2_5 0.43067655807339306f

__device__ inline unsigned cvt2(float x, float y) {
    float2 f; f.x = x; f.y = y;
    __hip_bfloat162 h = __float22bfloat162_rn(f);
    unsigned u; __builtin_memcpy(&u, &h, sizeof(u));
    return u;
}

// ---- one-time fp32 -> bf16 table conversion (8 elems/thread) ----
extern "C" __global__ __launch_bounds__(256)
void cvt_tables(const float* __restrict__ ai, const float* __restrict__ bi,
                const float* __restrict__ as, const float* __restrict__ bs,
                unsigned short* __restrict__ dst)
{
    const int t = blockIdx.x * 256 + threadIdx.x;   // 96000 threads
    const long e = (long)t * 8;
    const float* src;
    if      (e < 256000) src = ai + e;
    else if (e < 512000) src = bi + (e - 256000);
    else if (e < 640000) src = as + (e - 512000);
    else                 src = bs + (e - 640000);
    float4 f0 = *(const float4*)src;
    float4 f1 = *(const float4*)(src + 4);
    uint4 pk;
    pk.x = cvt2(f0.x, f0.y); pk.y = cvt2(f0.z, f0.w);
    pk.z = cvt2(f1.x, f1.y); pk.w = cvt2(f1.z, f1.w);
    *(uint4*)(dst + e) = pk;
}

// exact fp32 path for duplicate-timestamp pairs (dt==0, i<j):
// contribution = alpha_dot * exp(beta' * 14.306765580733931)   [= -log(1e-10)/log(5)]
__device__ float fixup_pair(const float* __restrict__ air,
                            const float* __restrict__ bir,
                            const float* __restrict__ asr,
                            const float* __restrict__ bsr) {
    float da = 0.f, db = 0.f;
#pragma unroll 8
    for (int k = 0; k < EMB; k += 4) {
        float4 a  = *(const float4*)(air + k);
        float4 s  = *(const float4*)(asr + k);
        float4 bq = *(const float4*)(bir + k);
        float4 tt = *(const float4*)(bsr + k);
        da += a.x * s.x + a.y * s.y + a.z * s.z + a.w * s.w;
        db += bq.x * tt.x + bq.y * tt.y + bq.z * tt.z + bq.w * tt.w;
    }
    float beta = fminf(fmaxf(db + 1.f, 0.f), 10.f);
    return da * __expf(beta * 14.30676558073393f);
}

// ---- half-tile (32 rows x 2 mats) staging: 64B per thread ----
// thread role: row = tid>>3 (0..31), mat = (tid>>2)&1, sq = tid&3
struct StageH { uint4 q0, q1, q2, q3; };

__device__ __forceinline__ StageH stageh_load(const int* __restrict__ binp,
                                              const char* __restrict__ tbc,
                                              int half, int row, long matb, int sq)
{
    const int arow = half * 32 + row;
    const long intr = binp[arow] + (long)binp[2 * SL + arow] * NSK;
    const char* p = tbc + matb + intr * 256 + sq * 64;
    StageH s;
    s.q0 = *(const uint4*)(p);      s.q1 = *(const uint4*)(p + 16);
    s.q2 = *(const uint4*)(p + 32); s.q3 = *(const uint4*)(p + 48);
    return s;
}

// proven swizzle (0 conflicts measured r1): 16B chunk c of row r stored at
// byte ((((c>>1)^(r&7)) + ((c&1)<<3)) << 4) within the row's 256B.
// thread writes chunks 4sq..4sq+3 -> wslot, wslot+128, wslot^16, (wslot^16)+128.
__device__ __forceinline__ void stageh_write(char* buf, int row, long matoff,
                                             int wslot, const StageH& s)
{
    char* p  = buf + matoff + row * 256 + wslot;
    char* px = buf + matoff + row * 256 + (wslot ^ 16);
    *(uint4*)(p)        = s.q0;  *(uint4*)(p + 128)  = s.q1;
    *(uint4*)(px)       = s.q2;  *(uint4*)(px + 128) = s.q3;
}

// ============================================================================
// hawkes_fused v9: NS=1 -> one block owns ALL i-tiles of its 64-j strip, so
// bias + duplicate-pair fp32 correction + sigmoid fuse into the tail and the
// finalize kernel + acc round-trip disappear. Main loop = the best-measured
// family (r0/r1): wave = 16-j strip reading the whole tile; ping-pong 32-row
// halves in a 32 KB LDS double buffer; 2-deep register prefetch; 1 barrier
// per half; verified conflict-free swizzle. Grid 1024 = exactly 4 blocks/CU.
// ============================================================================
extern "C" __global__ __launch_bounds__(256, 4)
void hawkes_fused(const int*   __restrict__ inp,     // (B,4,L) int32
                  const unsigned short* __restrict__ tb,  // bf16 tables
                  const float* __restrict__ pbase,
                  const float* __restrict__ sbase,
                  const float* __restrict__ ai, const float* __restrict__ as,
                  const float* __restrict__ bi, const float* __restrict__ bs,
                  float*       __restrict__ out)
{
    __shared__ uint4 ldsq[2048];                    // 32 KB: 2 bufs x (2 mats x 32 rows x 256B)
    char* ldsc = (char*)ldsq;

    const int bid  = blockIdx.x;                    // grid = 16 * NB = 1024
    const int b    = bid & (NB - 1);
    const int jt   = 15 - (bid >> 6);               // heavy j-tiles dispatch first
    const int tid  = threadIdx.x;
    const int w    = tid >> 6;                      // wave -> 16-j strip
    const int l    = tid & 63;
    const int quad = l >> 4;
    const int col  = l & 15;

    const int* __restrict__ binp = inp + b * 4 * SL;
    const char* __restrict__ tbc = (const char*)tb;

    const int jlane = jt * TI + w * 16 + col;
    const int sk_j  = binp[jlane];
    const int tj    = binp[3 * SL + jlane];

    // ---- B fragments (skill rows of this lane's j), direct from global ----
    short8 bfa[4], bfb[4];
    {
        const char* asr = tbc + AS_B + (long)sk_j * 256 + quad * 16;
        const char* bsr = tbc + BS_B + (long)sk_j * 256 + quad * 16;
#pragma unroll
        for (int ks = 0; ks < 4; ++ks) {
            bfa[ks] = *(const short8*)(asr + ks * 64);
            bfb[ks] = *(const short8*)(bsr + ks * 64);
        }
    }

    // ---- staging role ----
    const int  srow  = tid >> 3;                    // 0..31
    const long matb  = ((tid >> 2) & 1) ? (long)BI_B : (long)AI_B;
    const long matoff = ((tid >> 2) & 1) ? 8192 : 0;
    const int  sq    = tid & 3;
    const int  wslot = (((2 * sq) ^ (srow & 7)) << 4);

    // ---- lane-invariant swizzled read offsets (chunk c = 4ks+quad) ----
    int roff[4];
    {
        const int qh = quad >> 1, ql = quad & 1, c7 = col & 7;
#pragma unroll
        for (int ks = 0; ks < 4; ++ks)
            roff[ks] = col * 256 + ql * 128 + (((2 * ks + qh) ^ c7) << 4);
    }

    const int nh = 2 * (jt + 1);                    // halves; always even
    float sum = 0.f;

    // prolog: half 0 -> buf0; issue half-1 loads
    StageH sEven = stageh_load(binp, tbc, 0, srow, matb, sq);
    stageh_write(ldsc, srow, matoff, wslot, sEven);
    StageH sOdd;
    if (nh > 1) sOdd = stageh_load(binp, tbc, 1, srow, matb, sq);

#pragma unroll 1
    for (int t = 0; t <= jt; ++t) {
        const int h2 = 2 * t + 2;

#pragma unroll
        for (int ph = 0; ph < 2; ++ph) {
            __syncthreads();        // prev compute on target buf done; cur buf published
            if (ph == 0) {
                stageh_write(ldsc + 16384, srow, matoff, wslot, sOdd);   // half 2t+1
                if (h2 < nh) sEven = stageh_load(binp, tbc, h2, srow, matb, sq);
            } else {
                if (h2 < nh)     stageh_write(ldsc, srow, matoff, wslot, sEven); // half 2t+2
                if (h2 + 1 < nh) sOdd = stageh_load(binp, tbc, h2 + 1, srow, matb, sq);
            }

            const char* buf     = ldsc + (ph ? 16384 : 0);
            const int   rowbase = t * 64 + ph * 32;

#pragma unroll
            for (int isub = 0; isub < 2; ++isub) {
                short8 av[4], bv[4];
#pragma unroll
                for (int ks = 0; ks < 4; ++ks) {
                    av[ks] = *(const short8*)(buf + isub * 4096 + roff[ks]);
                    bv[ks] = *(const short8*)(buf + 8192 + isub * 4096 + roff[ks]);
                }
                const int4 t4 = *(const int4*)(binp + 3 * SL + rowbase + isub * 16 + quad * 4);

                floatx4 aa = {0.f, 0.f, 0.f, 0.f};
                floatx4 bb = {1.f, 1.f, 1.f, 1.f};   // folds the "+1.0"
#pragma unroll
                for (int ks = 0; ks < 4; ++ks) {
                    aa = __builtin_amdgcn_mfma_f32_16x16x32_bf16(av[ks], bfa[ks], aa, 0, 0, 0);
                    bb = __builtin_amdgcn_mfma_f32_16x16x32_bf16(bv[ks], bfb[ks], bb, 0, 0, 0);
                }
#pragma unroll
                for (int rr = 0; rr < 4; ++rr) {
                    const int ti = (rr == 0) ? t4.x : (rr == 1) ? t4.y : (rr == 2) ? t4.z : t4.w;
                    const int dt = tj - ti;
                    // sorted times => (i<j && dt>0) <=> dt>0 ; dt==0 handled below
                    float lc  = __log2f((float)dt);               // junk if dt<=0, discarded
                    float nb  = fminf(fmaxf(bb[rr], 0.f), 10.f) * (-INV_LOG2_5);
                    float arg = (dt > 0) ? nb * lc : -__builtin_inff();
                    sum += aa[rr] * __builtin_amdgcn_exp2f(arg);
                }
            }
        }
    }

    // ---- reduce the 4 quads holding the same j ----
    sum += __shfl_xor(sum, 16, 64);
    sum += __shfl_xor(sum, 32, 64);

    // ---- fused finalize: dup-pair fp32 correction + biases + sigmoid ----
    if (quad == 0) {
        float corr = 0.f;
        for (int i = jlane - 1; i >= 0 && binp[3 * SL + i] == tj; --i) {
            const int ski = binp[i], li = binp[2 * SL + i];
            const long intr = ski + (long)li * NSK;
            corr += fixup_pair(ai + intr * EMB, bi + intr * EMB,
                               as + (long)sk_j * EMB, bs + (long)sk_j * EMB);
        }
        const float x = pbase[binp[SL + jlane]] + sbase[sk_j] + sum + corr;
        out[b * SL + jlane] = 1.f / (1.f + __expf(-x));
    }
}

extern "C" void kernel_launch(void* const* d_in, const int* in_sizes, int n_in,
                              void* d_out, int out_size, void* d_ws, size_t ws_size,
                              hipStream_t stream) {
    const int*   inp = (const int*)d_in[0];
    const float* pb  = (const float*)d_in[1];
    const float* sb  = (const float*)d_in[2];
    const float* ai  = (const float*)d_in[3];
    const float* as  = (const float*)d_in[4];
    const float* bi  = (const float*)d_in[5];
    const float* bs  = (const float*)d_in[6];

    unsigned short* tb = (unsigned short*)d_ws;

    cvt_tables<<<dim3(96000 / 256), dim3(256), 0, stream>>>(ai, bi, as, bs, tb);
    hawkes_fused<<<dim3(16 * NB), dim3(256), 0, stream>>>(
        inp, tb, pb, sb, ai, as, bi, bs, (float*)d_out);
}